// Round 14
// baseline (223.622 us; speedup 1.0000x reference)
//
#include <hip/hip_runtime.h>
#include <hip/hip_bf16.h>
#include <cmath>

typedef unsigned short u16;
typedef __attribute__((ext_vector_type(8))) short short8v;
typedef __attribute__((ext_vector_type(8))) unsigned short ushort8v;
typedef __attribute__((ext_vector_type(4))) float f32x4;

#define NPIX 784      // 28*28
#define KP   800
#define NH   800
#define LSTR 424      // bf16 half-tile row stride (848 B rows)
#define B32OFF 54272  // f32 prefetch buffer offset (98304 B region)

__device__ __forceinline__ u16 f2bf(float f) {
    union { float f; unsigned int u; } v; v.f = f;
    unsigned int u = v.u;
    unsigned int r = (u + 0x7FFFu + ((u >> 16) & 1u)) >> 16;   // RNE
    return (u16)r;
}

__device__ __forceinline__ short8v cvt8(f32x4 v0, f32x4 v1) {
    union { __hip_bfloat162 h; ushort2 u; } a, b, c, d;
    a.h = __float22bfloat162_rn(make_float2(v0[0], v0[1]));
    b.h = __float22bfloat162_rn(make_float2(v0[2], v0[3]));
    c.h = __float22bfloat162_rn(make_float2(v1[0], v1[1]));
    d.h = __float22bfloat162_rn(make_float2(v1[2], v1[3]));
    short8v r;
    r[0] = (short)a.u.x; r[1] = (short)a.u.y; r[2] = (short)b.u.x; r[3] = (short)b.u.y;
    r[4] = (short)c.u.x; r[5] = (short)c.u.y; r[6] = (short)d.u.x; r[7] = (short)d.u.y;
    return r;
}

__device__ __forceinline__ void gload16(const float* g, char* l) {
    __builtin_amdgcn_global_load_lds(
        (const __attribute__((address_space(1))) unsigned int*)g,
        (__attribute__((address_space(3))) unsigned int*)l,
        16, 0, 0);
}

// ---------------------------------------------------------------------------
// Kernel 1: kre = Re(ifft2(ifftshift(tmask))); flag=1 if kre == delta.
// ---------------------------------------------------------------------------
__global__ void k_kre(const float* __restrict__ MRE, const float* __restrict__ MIM,
                      float* __restrict__ KRE, float* __restrict__ FLAG)
{
    __shared__ float msre[784], msim[784], tre[784], tim[784];
    __shared__ float c28[28], s28[28];
    __shared__ int smax;

    const int t = threadIdx.x;   // blockDim = 832
    if (t < 28) {
        float th = (float)t * (6.283185307179586f / 28.0f);
        s28[t] = sinf(th);
        c28[t] = cosf(th);
    }
    if (t == 0) smax = 0;
    if (t < 784) {
        int r = t / 28, c = t - r * 28;
        int idx = ((r + 14) % 28) * 28 + ((c + 14) % 28);   // ifftshift
        msre[t] = MRE[idx];
        msim[t] = MIM[idx];
    }
    __syncthreads();
    if (t < 784) {
        int u = t / 28, cc = t - u * 28;
        float re = 0.f, im = 0.f;
        int ph = 0;
        for (int v = 0; v < 28; ++v) {
            float cr = c28[ph], ci = s28[ph];
            float ar = msre[u * 28 + v], ai = msim[u * 28 + v];
            re += ar * cr - ai * ci;
            im += ar * ci + ai * cr;
            ph += cc; if (ph >= 28) ph -= 28;
        }
        tre[t] = re; tim[t] = im;
    }
    __syncthreads();
    float dev = 0.f;
    if (t < 784) {
        int pr = t / 28, pc = t - pr * 28;
        float s = 0.f;
        int ph = 0;
        for (int u = 0; u < 28; ++u) {
            s += tre[u * 28 + pc] * c28[ph] - tim[u * 28 + pc] * s28[ph];
            ph += pr; if (ph >= 28) ph -= 28;
        }
        s *= (1.0f / 784.0f);
        KRE[t] = s;
        dev = fabsf(s - (t == 0 ? 1.0f : 0.0f));
    }
    #pragma unroll
    for (int m = 32; m >= 1; m >>= 1) dev = fmaxf(dev, __shfl_xor(dev, m, 64));
    if ((t & 63) == 0) atomicMax(&smax, __float_as_int(dev));
    __syncthreads();
    if (t == 0) FLAG[0] = (__int_as_float(smax) < 1e-4f) ? 1.0f : 0.0f;
}

// ---------------------------------------------------------------------------
// Kernel 2: w1_eff packed into MFMA B-fragment order, bf16 (k>=784 -> 0).
// ---------------------------------------------------------------------------
__global__ void k_w1pack(const float* __restrict__ W1, const float* __restrict__ KRE,
                         const float* __restrict__ FLAG, u16* __restrict__ W1P)
{
    const int c = blockIdx.x;    // 0..799
    const int t = threadIdx.x;   // 128
    const bool delta = (FLAG[0] > 0.5f);
    __shared__ float w1d[56 * 56];
    __shared__ float kr[784];

    if (delta) {
        if (t < 100) {
            int k0 = t * 8;
            ushort8v h;
            if (k0 + 7 < NPIX) {
                const float4* wp = (const float4*)(W1 + (size_t)c * NPIX + k0);
                float4 a = wp[0], b = wp[1];
                h[0] = f2bf(a.x); h[1] = f2bf(a.y); h[2] = f2bf(a.z); h[3] = f2bf(a.w);
                h[4] = f2bf(b.x); h[5] = f2bf(b.y); h[6] = f2bf(b.z); h[7] = f2bf(b.w);
            } else {
                #pragma unroll
                for (int e = 0; e < 8; ++e) {
                    int k = k0 + e;
                    h[e] = (k < NPIX) ? f2bf(W1[(size_t)c * NPIX + k]) : (u16)0;
                }
            }
            int kf = k0 >> 5, r = k0 & 31;
            int l  = ((r >> 3) << 4) | (c & 15);
            int nf = c >> 4;
            ((ushort8v*)W1P)[(nf * 25 + kf) * 64 + l] = h;
        }
        return;
    }
    for (int i = t; i < 784; i += 128) kr[i] = KRE[i];
    for (int i = t; i < 3136; i += 128) {
        int r = i / 56, cc = i - r * 56;
        w1d[i] = W1[(size_t)c * NPIX + (r % 28) * 28 + (cc % 28)];
    }
    __syncthreads();
    for (int k = t; k < KP; k += 128) {
        float v = 0.f;
        if (k < NPIX) {
            int krr = k / 28, kcc = k - krr * 28;
            for (int dr = 0; dr < 28; ++dr) {
                const float* wrow = &w1d[(krr + dr) * 56 + kcc];
                const float* krow = &kr[dr * 28];
                #pragma unroll 4
                for (int dc = 0; dc < 28; ++dc) v += wrow[dc] * krow[dc];
            }
        }
        int kf = k >> 5, r = k & 31;
        int l  = ((r >> 3) << 4) | (c & 15);
        int nf = c >> 4;
        W1P[(size_t)(((nf * 25 + kf) * 64 + l) << 3) | (r & 7)] = f2bf(v);
    }
}

// ---------------------------------------------------------------------------
// Kernel 2b: pack W4 per (wave, kt2).
// ---------------------------------------------------------------------------
__global__ void k_w4pack2(const float* __restrict__ W4, u16* __restrict__ W4P2)
{
    int i = blockIdx.x * 256 + threadIdx.x;   // (w*3+kt2)*64 + l, 1920 total
    if (i >= 1920) return;
    int l = i & 63, wk = i >> 6;
    int w = wk / 3, kt2 = wk - w * 3;
    int lc = l & 15, lk = l >> 4;
    ushort8v h;
    #pragma unroll
    for (int e = 0; e < 8; ++e) {
        int k = w * 80 + kt2 * 32 + lk * 8 + e;
        h[e] = (lc < 10 && k < 800) ? f2bf(W4[lc * NH + k]) : (u16)0;
    }
    ((ushort8v*)W4P2)[i] = h;
}

// ---------------------------------------------------------------------------
// Per-tile epilogue: relu+bias -> per-wave strip -> GEMM2 MFMA -> PL ->
// combine + log_softmax. (r12/r13-verified layout.)
// ---------------------------------------------------------------------------
__device__ __forceinline__ void tail_epilogue(
    f32x4 (&acc)[4][5], u16* As, const float* __restrict__ B1,
    const short8v* __restrict__ WP, const float* __restrict__ B4,
    float* __restrict__ OUT, int rowbase, int t, int w, int l, int lc, int lk)
{
    u16* strip = As + w * 1536;                // [16][96] bf16 per wave
    {   // zero pad cols 80..95
        uint2 z = make_uint2(0u, 0u);
        *(uint2*)((char*)strip + (l >> 2) * 192 + 160 + (l & 3) * 8) = z;
    }
    float bn[5];
    #pragma unroll
    for (int n = 0; n < 5; ++n) bn[n] = B1[w * 80 + n * 16 + lc];
    short8v w4f[3];
    #pragma unroll
    for (int kt2 = 0; kt2 < 3; ++kt2)
        w4f[kt2] = WP[(w * 3 + kt2) * 64 + l];

    f32x4 pc[4];
    #pragma unroll
    for (int m = 0; m < 4; ++m) {
        #pragma unroll
        for (int n = 0; n < 5; ++n)
            #pragma unroll
            for (int j = 0; j < 4; ++j)
                strip[(lk * 4 + j) * 96 + n * 16 + lc] = f2bf(fmaxf(acc[m][n][j] + bn[n], 0.0f));
        pc[m] = (f32x4)(0.0f);
        #pragma unroll
        for (int kt2 = 0; kt2 < 3; ++kt2) {
            short8v a2 = *(const short8v*)(strip + lc * 96 + kt2 * 32 + lk * 8);
            pc[m] = __builtin_amdgcn_mfma_f32_16x16x32_bf16(a2, w4f[kt2], pc[m], 0, 0, 0);
        }
    }
    __syncthreads();                           // strips dead; PL overlays

    float* PLf = (float*)As + w * 640;         // [64][10] f32 per wave
    if (lc < 10) {
        #pragma unroll
        for (int m = 0; m < 4; ++m)
            #pragma unroll
            for (int j = 0; j < 4; ++j)
                PLf[(m * 16 + lk * 4 + j) * 10 + lc] = pc[m][j];
    }
    __syncthreads();

    if (t < 64) {
        float lg[10];
        #pragma unroll
        for (int o = 0; o < 10; ++o) lg[o] = B4[o];
        #pragma unroll
        for (int w2 = 0; w2 < 10; ++w2) {
            const float* PLw = (const float*)As + w2 * 640;
            #pragma unroll
            for (int o = 0; o < 10; ++o) lg[o] += PLw[t * 10 + o];
        }
        float mx = lg[0];
        #pragma unroll
        for (int o = 1; o < 10; ++o) mx = fmaxf(mx, lg[o]);
        float se = 0.f;
        #pragma unroll
        for (int o = 0; o < 10; ++o) se += expf(lg[o] - mx);
        float lse = logf(se);
        float* op = OUT + (size_t)(rowbase + t) * 10;
        #pragma unroll
        for (int o = 0; o < 10; ++o) op[o] = lg[o] - mx - lse;
    }
    __syncthreads();                           // PL reads done before reuse
}

// ---------------------------------------------------------------------------
// Kernel 3: persistent 2-tile blocks. grid=256, each block: two 64-row tiles.
// v14 = v13 per-tile machinery + tile-2 half-0 prefetched in f32 via
//       gload_lds (zero registers) into a disjoint 98 KB LDS region during
//       tile-1's kt 0..9 (any scheduling is correct; one vmcnt(0)+barrier
//       before tile-2 compute). Tile-2 kt 0..11 reads f32+cvt8 (v9-verified
//       swizzle); other three stages stay serial (v13-verified).
// ---------------------------------------------------------------------------
__global__ __launch_bounds__(640) __attribute__((amdgpu_waves_per_eu(3, 3)))
void k_main(
    const float* __restrict__ X, const u16* __restrict__ W1P,
    const u16* __restrict__ W4P2, const float* __restrict__ B1,
    const float* __restrict__ B4, float* __restrict__ OUT)
{
    __shared__ __align__(16) char SMEM[152576];   // 54272 bf16 tile + 98304 f32
    u16*  As   = (u16*)SMEM;
    char* b32  = SMEM + B32OFF;

    const int t = threadIdx.x;
    const int row0 = blockIdx.x * 128;
    const int l = t & 63, w = t >> 6;
    const int lc = l & 15, lk = l >> 4;

    f32x4 acc[4][5];
    #pragma unroll
    for (int m = 0; m < 4; ++m)
        #pragma unroll
        for (int n = 0; n < 5; ++n) acc[m][n] = (f32x4)(0.0f);

    const short8v* BP = (const short8v*)W1P;
    const short8v* WP = (const short8v*)W4P2;
    short8v bb[2][5];
    #pragma unroll
    for (int n = 0; n < 5; ++n)
        bb[0][n] = BP[((w * 5 + n) * 25 + 0) * 64 + l];

    // ---- t2h0 prefetch geometry: 6144 granules of 16B over [64][96] ----
    // granule g = t + 640*kt (kt 0..9; kt==9 guarded t<384); linear LDS dest,
    // XOR-swizzled global source (v9 pattern).
    int pr_row = t / 96;                 // running row
    int pr_rem = t - pr_row * 96;        // running granule-col
    const char* x2b = (const char*)(X + (size_t)(row0 + 64) * NPIX);

    // ================= TILE 1 =================
    // ---- stage t1 half-0: cols [0,384) ----
    #pragma unroll
    for (int i = 0; i < 5; ++i) {
        int u = t + 640 * i;
        if (i < 4 || u < 3072) {
            int row = u / 48, uc = u - row * 48;
            const float* g = X + (size_t)(row0 + row) * NPIX + uc * 8;
            f32x4 v0 = *(const f32x4*)(g);
            f32x4 v1 = *(const f32x4*)(g + 4);
            *(short8v*)(As + row * LSTR + uc * 8) = cvt8(v0, v1);
        }
    }
    asm volatile("s_waitcnt lgkmcnt(0)" ::: "memory");
    __builtin_amdgcn_s_barrier();
    __builtin_amdgcn_sched_barrier(0);

    // ---- t1 kt 0..11 + t2h0 prefetch issues at kt 0..9 ----
    #pragma unroll
    for (int kt = 0; kt < 12; ++kt) {
        #pragma unroll
        for (int n = 0; n < 5; ++n)
            bb[(kt + 1) & 1][n] = BP[((w * 5 + n) * 25 + (kt + 1)) * 64 + l];
        if (kt < 10) {
            if (kt < 9 || t < 384) {
                int bcol = (pr_rem * 16) ^ ((pr_row & 7) << 4);
                gload16((const float*)(x2b + (size_t)pr_row * 3136 + bcol),
                        b32 + 16 * t + kt * 10240);
            }
            pr_row += 6; pr_rem += 64;
            if (pr_rem >= 96) { pr_rem -= 96; pr_row += 1; }
        }
        const u16* ab = As + lc * LSTR + kt * 32 + lk * 8;
        __builtin_amdgcn_s_setprio(1);
        #pragma unroll
        for (int m = 0; m < 4; ++m) {
            short8v a = *(const short8v*)(ab + m * (16 * LSTR));
            #pragma unroll
            for (int n = 0; n < 5; ++n)
                acc[m][n] = __builtin_amdgcn_mfma_f32_16x16x32_bf16(a, bb[kt & 1][n], acc[m][n], 0, 0, 0);
        }
        __builtin_amdgcn_s_setprio(0);
    }
    asm volatile("s_waitcnt lgkmcnt(0)" ::: "memory");
    __builtin_amdgcn_s_barrier();
    __builtin_amdgcn_sched_barrier(0);

    // ---- stage t1 half-1: cols [384,800), pad>=784 -> 0 ----
    #pragma unroll
    for (int i = 0; i < 6; ++i) {
        int u = t + 640 * i;
        if (i < 5 || u < 3328) {
            int row = u / 52, uc = u - row * 52;
            int gcol = 384 + uc * 8;
            short8v hv;
            if (gcol < NPIX) {
                const float* g = X + (size_t)(row0 + row) * NPIX + gcol;
                f32x4 v0 = *(const f32x4*)(g);
                f32x4 v1 = *(const f32x4*)(g + 4);
                hv = cvt8(v0, v1);
            } else {
                hv = (short8v)(0);
            }
            *(short8v*)(As + row * LSTR + uc * 8) = hv;
        }
    }
    asm volatile("s_waitcnt lgkmcnt(0)" ::: "memory");
    __builtin_amdgcn_s_barrier();
    __builtin_amdgcn_sched_barrier(0);

    // ---- t1 kt 12..24 ----
    #pragma unroll
    for (int kt = 12; kt < 25; ++kt) {
        if (kt < 24) {
            #pragma unroll
            for (int n = 0; n < 5; ++n)
                bb[(kt + 1) & 1][n] = BP[((w * 5 + n) * 25 + (kt + 1)) * 64 + l];
        }
        const u16* ab = As + lc * LSTR + (kt - 12) * 32 + lk * 8;
        __builtin_amdgcn_s_setprio(1);
        #pragma unroll
        for (int m = 0; m < 4; ++m) {
            short8v a = *(const short8v*)(ab + m * (16 * LSTR));
            #pragma unroll
            for (int n = 0; n < 5; ++n)
                acc[m][n] = __builtin_amdgcn_mfma_f32_16x16x32_bf16(a, bb[kt & 1][n], acc[m][n], 0, 0, 0);
        }
        __builtin_amdgcn_s_setprio(0);
    }
    // preload bb for t2 kt0 (covered by t1 epilogue work)
    #pragma unroll
    for (int n = 0; n < 5; ++n)
        bb[0][n] = BP[((w * 5 + n) * 25 + 0) * 64 + l];

    asm volatile("s_waitcnt lgkmcnt(0)" ::: "memory");
    __builtin_amdgcn_s_barrier();              // t1 x reads done; As dead
    __builtin_amdgcn_sched_barrier(0);

    // ---- t1 epilogue (writes OUT rows row0..row0+63) ----
    tail_epilogue(acc, As, B1, WP, B4, OUT, row0, t, w, l, lc, lk);

    // ================= TILE 2 =================
    #pragma unroll
    for (int m = 0; m < 4; ++m)
        #pragma unroll
        for (int n = 0; n < 5; ++n) acc[m][n] = (f32x4)(0.0f);

    asm volatile("s_waitcnt vmcnt(0)" ::: "memory");   // t2h0 landed
    __builtin_amdgcn_s_barrier();
    __builtin_amdgcn_sched_barrier(0);

    // ---- t2 kt 0..11 from f32 buffer (v9-verified swizzled read) ----
    const int aq0 = (lk * 32) ^ ((lc & 7) << 4);
    #pragma unroll
    for (int kt = 0; kt < 12; ++kt) {
        #pragma unroll
        for (int n = 0; n < 5; ++n)
            bb[(kt + 1) & 1][n] = BP[((w * 5 + n) * 25 + (kt + 1)) * 64 + l];
        const char* ab = b32 + lc * 1536 + kt * 128;
        __builtin_amdgcn_s_setprio(1);
        #pragma unroll
        for (int m = 0; m < 4; ++m) {
            f32x4 v0 = *(const f32x4*)(ab + m * 24576 + aq0);
            f32x4 v1 = *(const f32x4*)(ab + m * 24576 + (aq0 ^ 16));
            short8v a = cvt8(v0, v1);
            #pragma unroll
            for (int n = 0; n < 5; ++n)
                acc[m][n] = __builtin_amdgcn_mfma_f32_16x16x32_bf16(a, bb[kt & 1][n], acc[m][n], 0, 0, 0);
        }
        __builtin_amdgcn_s_setprio(0);
    }
    __builtin_amdgcn_s_barrier();              // (no LDS writes pending; cheap)
    __builtin_amdgcn_sched_barrier(0);

    // ---- stage t2 half-1 into As (rows row0+64..) ----
    #pragma unroll
    for (int i = 0; i < 6; ++i) {
        int u = t + 640 * i;
        if (i < 5 || u < 3328) {
            int row = u / 52, uc = u - row * 52;
            int gcol = 384 + uc * 8;
            short8v hv;
            if (gcol < NPIX) {
                const float* g = X + (size_t)(row0 + 64 + row) * NPIX + gcol;
                f32x4 v0 = *(const f32x4*)(g);
                f32x4 v1 = *(const f32x4*)(g + 4);
                hv = cvt8(v0, v1);
            } else {
                hv = (short8v)(0);
            }
            *(short8v*)(As + row * LSTR + uc * 8) = hv;
        }
    }
    asm volatile("s_waitcnt lgkmcnt(0)" ::: "memory");
    __builtin_amdgcn_s_barrier();
    __builtin_amdgcn_sched_barrier(0);

    // ---- t2 kt 12..24 ----
    #pragma unroll
    for (int kt = 12; kt < 25; ++kt) {
        if (kt < 24) {
            #pragma unroll
            for (int n = 0; n < 5; ++n)
                bb[(kt + 1) & 1][n] = BP[((w * 5 + n) * 25 + (kt + 1)) * 64 + l];
        }
        const u16* ab = As + lc * LSTR + (kt - 12) * 32 + lk * 8;
        __builtin_amdgcn_s_setprio(1);
        #pragma unroll
        for (int m = 0; m < 4; ++m) {
            short8v a = *(const short8v*)(ab + m * (16 * LSTR));
            #pragma unroll
            for (int n = 0; n < 5; ++n)
                acc[m][n] = __builtin_amdgcn_mfma_f32_16x16x32_bf16(a, bb[kt & 1][n], acc[m][n], 0, 0, 0);
        }
        __builtin_amdgcn_s_setprio(0);
    }
    asm volatile("s_waitcnt lgkmcnt(0)" ::: "memory");
    __builtin_amdgcn_s_barrier();
    __builtin_amdgcn_sched_barrier(0);

    // ---- t2 epilogue (writes OUT rows row0+64..row0+127) ----
    tail_epilogue(acc, As, B1, WP, B4, OUT, row0 + 64, t, w, l, lc, lk);
}

// ---------------------------------------------------------------------------
extern "C" void kernel_launch(void* const* d_in, const int* in_sizes, int n_in,
                              void* d_out, int out_size, void* d_ws, size_t ws_size,
                              hipStream_t stream)
{
    const float* X   = (const float*)d_in[0];
    const float* MRE = (const float*)d_in[1];
    const float* MIM = (const float*)d_in[2];
    const float* W1  = (const float*)d_in[3];
    const float* B1  = (const float*)d_in[4];
    const float* W4  = (const float*)d_in[5];
    const float* B4  = (const float*)d_in[6];
    float* OUT = (float*)d_out;

    float* kre  = (float*)d_ws;                          // 784 f32
    float* flag = kre + 784;                             // 1 f32
    u16*   w1p  = (u16*)((char*)d_ws + 4096);            // 1.28 MB
    u16*   w4p2 = (u16*)((char*)d_ws + 4096 + 1310720);  // 30720 B

    k_kre<<<1, 832, 0, stream>>>(MRE, MIM, kre, flag);
    k_w1pack<<<800, 128, 0, stream>>>(W1, kre, flag, w1p);
    k_w4pack2<<<8, 256, 0, stream>>>(W4, w4p2);
    k_main<<<256, 640, 0, stream>>>(X, w1p, w4p2, B1, B4, OUT);
}

// Round 15
// 68.856 us; speedup vs baseline: 3.2477x; 3.2477x over previous
//
#include <hip/hip_runtime.h>
#include <hip/hip_bf16.h>
#include <cmath>

typedef unsigned short u16;
typedef __attribute__((ext_vector_type(8))) short short8v;
typedef __attribute__((ext_vector_type(8))) unsigned short ushort8v;
typedef __attribute__((ext_vector_type(4))) float f32x4;

#define NPIX 784      // 28*28
#define KP   800
#define NH   800
#define LSTR 424      // LDS half-tile row stride, bf16 (848 B rows)

__device__ __forceinline__ u16 f2bf(float f) {
    union { float f; unsigned int u; } v; v.f = f;
    unsigned int u = v.u;
    unsigned int r = (u + 0x7FFFu + ((u >> 16) & 1u)) >> 16;   // RNE
    return (u16)r;
}

__device__ __forceinline__ short8v cvt8(f32x4 v0, f32x4 v1) {
    union { __hip_bfloat162 h; ushort2 u; } a, b, c, d;
    a.h = __float22bfloat162_rn(make_float2(v0[0], v0[1]));
    b.h = __float22bfloat162_rn(make_float2(v0[2], v0[3]));
    c.h = __float22bfloat162_rn(make_float2(v1[0], v1[1]));
    d.h = __float22bfloat162_rn(make_float2(v1[2], v1[3]));
    short8v r;
    r[0] = (short)a.u.x; r[1] = (short)a.u.y; r[2] = (short)b.u.x; r[3] = (short)b.u.y;
    r[4] = (short)c.u.x; r[5] = (short)c.u.y; r[6] = (short)d.u.x; r[7] = (short)d.u.y;
    return r;
}

// ---------------------------------------------------------------------------
// Kernel 1: kre = Re(ifft2(ifftshift(tmask))); flag=1 if kre == delta.
// ---------------------------------------------------------------------------
__global__ void k_kre(const float* __restrict__ MRE, const float* __restrict__ MIM,
                      float* __restrict__ KRE, float* __restrict__ FLAG)
{
    __shared__ float msre[784], msim[784], tre[784], tim[784];
    __shared__ float c28[28], s28[28];
    __shared__ int smax;

    const int t = threadIdx.x;   // blockDim = 832
    if (t < 28) {
        float th = (float)t * (6.283185307179586f / 28.0f);
        s28[t] = sinf(th);
        c28[t] = cosf(th);
    }
    if (t == 0) smax = 0;
    if (t < 784) {
        int r = t / 28, c = t - r * 28;
        int idx = ((r + 14) % 28) * 28 + ((c + 14) % 28);   // ifftshift
        msre[t] = MRE[idx];
        msim[t] = MIM[idx];
    }
    __syncthreads();
    if (t < 784) {
        int u = t / 28, cc = t - u * 28;
        float re = 0.f, im = 0.f;
        int ph = 0;
        for (int v = 0; v < 28; ++v) {
            float cr = c28[ph], ci = s28[ph];
            float ar = msre[u * 28 + v], ai = msim[u * 28 + v];
            re += ar * cr - ai * ci;
            im += ar * ci + ai * cr;
            ph += cc; if (ph >= 28) ph -= 28;
        }
        tre[t] = re; tim[t] = im;
    }
    __syncthreads();
    float dev = 0.f;
    if (t < 784) {
        int pr = t / 28, pc = t - pr * 28;
        float s = 0.f;
        int ph = 0;
        for (int u = 0; u < 28; ++u) {
            s += tre[u * 28 + pc] * c28[ph] - tim[u * 28 + pc] * s28[ph];
            ph += pr; if (ph >= 28) ph -= 28;
        }
        s *= (1.0f / 784.0f);
        KRE[t] = s;
        dev = fabsf(s - (t == 0 ? 1.0f : 0.0f));
    }
    #pragma unroll
    for (int m = 32; m >= 1; m >>= 1) dev = fmaxf(dev, __shfl_xor(dev, m, 64));
    if ((t & 63) == 0) atomicMax(&smax, __float_as_int(dev));
    __syncthreads();
    if (t == 0) FLAG[0] = (__int_as_float(smax) < 1e-4f) ? 1.0f : 0.0f;
}

// ---------------------------------------------------------------------------
// Kernel 2: w1_eff packed into MFMA B-fragment order, bf16 (k>=784 -> 0).
// ---------------------------------------------------------------------------
__global__ void k_w1pack(const float* __restrict__ W1, const float* __restrict__ KRE,
                         const float* __restrict__ FLAG, u16* __restrict__ W1P)
{
    const int c = blockIdx.x;    // 0..799
    const int t = threadIdx.x;   // 128
    const bool delta = (FLAG[0] > 0.5f);
    __shared__ float w1d[56 * 56];
    __shared__ float kr[784];

    if (delta) {
        if (t < 100) {
            int k0 = t * 8;
            ushort8v h;
            if (k0 + 7 < NPIX) {
                const float4* wp = (const float4*)(W1 + (size_t)c * NPIX + k0);
                float4 a = wp[0], b = wp[1];
                h[0] = f2bf(a.x); h[1] = f2bf(a.y); h[2] = f2bf(a.z); h[3] = f2bf(a.w);
                h[4] = f2bf(b.x); h[5] = f2bf(b.y); h[6] = f2bf(b.z); h[7] = f2bf(b.w);
            } else {
                #pragma unroll
                for (int e = 0; e < 8; ++e) {
                    int k = k0 + e;
                    h[e] = (k < NPIX) ? f2bf(W1[(size_t)c * NPIX + k]) : (u16)0;
                }
            }
            int kf = k0 >> 5, r = k0 & 31;
            int l  = ((r >> 3) << 4) | (c & 15);
            int nf = c >> 4;
            ((ushort8v*)W1P)[(nf * 25 + kf) * 64 + l] = h;
        }
        return;
    }
    for (int i = t; i < 784; i += 128) kr[i] = KRE[i];
    for (int i = t; i < 3136; i += 128) {
        int r = i / 56, cc = i - r * 56;
        w1d[i] = W1[(size_t)c * NPIX + (r % 28) * 28 + (cc % 28)];
    }
    __syncthreads();
    for (int k = t; k < KP; k += 128) {
        float v = 0.f;
        if (k < NPIX) {
            int krr = k / 28, kcc = k - krr * 28;
            for (int dr = 0; dr < 28; ++dr) {
                const float* wrow = &w1d[(krr + dr) * 56 + kcc];
                const float* krow = &kr[dr * 28];
                #pragma unroll 4
                for (int dc = 0; dc < 28; ++dc) v += wrow[dc] * krow[dc];
            }
        }
        int kf = k >> 5, r = k & 31;
        int l  = ((r >> 3) << 4) | (c & 15);
        int nf = c >> 4;
        W1P[(size_t)(((nf * 25 + kf) * 64 + l) << 3) | (r & 7)] = f2bf(v);
    }
}

// ---------------------------------------------------------------------------
// Kernel 2b: pack W4 per (wave, kt2): W4P2[((w*3+kt2)*64+l)*8+e] =
//   (o<10 && k<800) ? bf16(W4[o][k]) : 0,  k = w*80 + kt2*32 + lk*8 + e, o=lc.
// ---------------------------------------------------------------------------
__global__ void k_w4pack2(const float* __restrict__ W4, u16* __restrict__ W4P2)
{
    int i = blockIdx.x * 256 + threadIdx.x;   // (w*3+kt2)*64 + l, 1920 total
    if (i >= 1920) return;
    int l = i & 63, wk = i >> 6;
    int w = wk / 3, kt2 = wk - w * 3;
    int lc = l & 15, lk = l >> 4;
    ushort8v h;
    #pragma unroll
    for (int e = 0; e < 8; ++e) {
        int k = w * 80 + kt2 * 32 + lk * 8 + e;
        h[e] = (lc < 10 && k < 800) ? f2bf(W4[lc * NH + k]) : (u16)0;
    }
    ((ushort8v*)W4P2)[i] = h;
}

// ---------------------------------------------------------------------------
// Kernel 3: fused GEMM1 + relu + per-wave GEMM2 + log_softmax.
// v15 = v13 (proven best: 68.8 us) with PL in its OWN LDS region (no overlay
//       of the strip area) -> one fewer __syncthreads in the epilogue.
//       Register envelope identical to v13 (acc 80 AGPR + bb 40 + <=10
//       transients = the measured non-spill set). Half-K LDS tile, serial
//       half staging (proven equal to pipelined within this envelope),
//       depth-1 B prefetch, raw barriers, setprio on MFMA clusters.
// ---------------------------------------------------------------------------
__global__ __launch_bounds__(640) __attribute__((amdgpu_waves_per_eu(3, 3)))
void k_main(
    const float* __restrict__ X, const u16* __restrict__ W1P,
    const u16* __restrict__ W4P2, const float* __restrict__ B1,
    const float* __restrict__ B4, float* __restrict__ OUT)
{
    __shared__ __align__(16) u16 As[64 * LSTR];           // 54272 B
    __shared__ __align__(16) float PL2[10 * 64 * 10];     // 25600 B, per-wave [64][10]
    const int t = threadIdx.x;
    const int row0 = blockIdx.x * 64;
    const int l = t & 63, w = t >> 6;
    const int lc = l & 15, lk = l >> 4;

    f32x4 acc[4][5];
    #pragma unroll
    for (int m = 0; m < 4; ++m)
        #pragma unroll
        for (int n = 0; n < 5; ++n) acc[m][n] = (f32x4)(0.0f);

    const short8v* BP = (const short8v*)W1P;
    short8v bb[2][5];
    #pragma unroll
    for (int n = 0; n < 5; ++n)
        bb[0][n] = BP[((w * 5 + n) * 25 + 0) * 64 + l];

    // ---- stage half-0: cols [0,384) = 3072 units of 8 f32 ----
    #pragma unroll
    for (int i = 0; i < 5; ++i) {
        int u = t + 640 * i;
        if (i < 4 || u < 3072) {
            int row = u / 48, uc = u - row * 48;
            const float* g = X + (size_t)(row0 + row) * NPIX + uc * 8;
            f32x4 v0 = *(const f32x4*)(g);
            f32x4 v1 = *(const f32x4*)(g + 4);
            *(short8v*)(As + row * LSTR + uc * 8) = cvt8(v0, v1);
        }
    }
    asm volatile("s_waitcnt lgkmcnt(0)" ::: "memory");
    __builtin_amdgcn_s_barrier();
    __builtin_amdgcn_sched_barrier(0);

    // ---- kt 0..11 (half-0), depth-1 B prefetch ----
    #pragma unroll
    for (int kt = 0; kt < 12; ++kt) {
        #pragma unroll
        for (int n = 0; n < 5; ++n)
            bb[(kt + 1) & 1][n] = BP[((w * 5 + n) * 25 + (kt + 1)) * 64 + l];
        const u16* ab = As + lc * LSTR + kt * 32 + lk * 8;
        __builtin_amdgcn_s_setprio(1);
        #pragma unroll
        for (int m = 0; m < 4; ++m) {
            short8v a = *(const short8v*)(ab + m * (16 * LSTR));
            #pragma unroll
            for (int n = 0; n < 5; ++n)
                acc[m][n] = __builtin_amdgcn_mfma_f32_16x16x32_bf16(a, bb[kt & 1][n], acc[m][n], 0, 0, 0);
        }
        __builtin_amdgcn_s_setprio(0);
    }
    asm volatile("s_waitcnt lgkmcnt(0)" ::: "memory");
    __builtin_amdgcn_s_barrier();              // half-0 reads done everywhere
    __builtin_amdgcn_sched_barrier(0);

    // ---- stage half-1: cols [384,800) = 3328 units (52/row); >=784 -> 0 ----
    #pragma unroll
    for (int i = 0; i < 6; ++i) {
        int u = t + 640 * i;
        if (i < 5 || u < 3328) {
            int row = u / 52, uc = u - row * 52;
            int gcol = 384 + uc * 8;
            short8v hv;
            if (gcol < NPIX) {
                const float* g = X + (size_t)(row0 + row) * NPIX + gcol;
                f32x4 v0 = *(const f32x4*)(g);
                f32x4 v1 = *(const f32x4*)(g + 4);
                hv = cvt8(v0, v1);
            } else {
                hv = (short8v)(0);
            }
            *(short8v*)(As + row * LSTR + uc * 8) = hv;
        }
    }
    asm volatile("s_waitcnt lgkmcnt(0)" ::: "memory");
    __builtin_amdgcn_s_barrier();              // half-1 visible
    __builtin_amdgcn_sched_barrier(0);

    // ---- kt 12..24 (half-1) ----
    #pragma unroll
    for (int kt = 12; kt < 25; ++kt) {
        if (kt < 24) {
            #pragma unroll
            for (int n = 0; n < 5; ++n)
                bb[(kt + 1) & 1][n] = BP[((w * 5 + n) * 25 + (kt + 1)) * 64 + l];
        }
        const u16* ab = As + lc * LSTR + (kt - 12) * 32 + lk * 8;
        __builtin_amdgcn_s_setprio(1);
        #pragma unroll
        for (int m = 0; m < 4; ++m) {
            short8v a = *(const short8v*)(ab + m * (16 * LSTR));
            #pragma unroll
            for (int n = 0; n < 5; ++n)
                acc[m][n] = __builtin_amdgcn_mfma_f32_16x16x32_bf16(a, bb[kt & 1][n], acc[m][n], 0, 0, 0);
        }
        __builtin_amdgcn_s_setprio(0);
    }
    asm volatile("s_waitcnt lgkmcnt(0)" ::: "memory");
    __builtin_amdgcn_s_barrier();              // all x reads done; As dead
    __builtin_amdgcn_sched_barrier(0);

    // ---- GEMM2 (per-wave strip transpose; r12/r13-verified layout) ----
    u16* strip = As + w * 1536;                // [16][96] bf16 per wave
    {   // zero pad cols 80..95
        uint2 z = make_uint2(0u, 0u);
        *(uint2*)((char*)strip + (l >> 2) * 192 + 160 + (l & 3) * 8) = z;
    }
    float bn[5];
    #pragma unroll
    for (int n = 0; n < 5; ++n) bn[n] = B1[w * 80 + n * 16 + lc];
    const short8v* WP = (const short8v*)W4P2;
    short8v w4f[3];
    #pragma unroll
    for (int kt2 = 0; kt2 < 3; ++kt2)
        w4f[kt2] = WP[(w * 3 + kt2) * 64 + l];

    float* PLf = PL2 + w * 640;                // [64][10] f32 per wave, own region
    #pragma unroll
    for (int m = 0; m < 4; ++m) {
        #pragma unroll
        for (int n = 0; n < 5; ++n)
            #pragma unroll
            for (int j = 0; j < 4; ++j)
                strip[(lk * 4 + j) * 96 + n * 16 + lc] = f2bf(fmaxf(acc[m][n][j] + bn[n], 0.0f));
        f32x4 pc = (f32x4)(0.0f);
        #pragma unroll
        for (int kt2 = 0; kt2 < 3; ++kt2) {
            short8v a2 = *(const short8v*)(strip + lc * 96 + kt2 * 32 + lk * 8);
            pc = __builtin_amdgcn_mfma_f32_16x16x32_bf16(a2, w4f[kt2], pc, 0, 0, 0);
        }
        if (lc < 10) {
            #pragma unroll
            for (int j = 0; j < 4; ++j)
                PLf[(m * 16 + lk * 4 + j) * 10 + lc] = pc[j];
        }
    }
    __syncthreads();

    // ---- combine + bias + log_softmax, one row per thread ----
    if (t < 64) {
        float lg[10];
        #pragma unroll
        for (int o = 0; o < 10; ++o) lg[o] = B4[o];
        #pragma unroll
        for (int w2 = 0; w2 < 10; ++w2) {
            const float* PLw = PL2 + w2 * 640;
            #pragma unroll
            for (int o = 0; o < 10; ++o) lg[o] += PLw[t * 10 + o];
        }
        float mx = lg[0];
        #pragma unroll
        for (int o = 1; o < 10; ++o) mx = fmaxf(mx, lg[o]);
        float se = 0.f;
        #pragma unroll
        for (int o = 0; o < 10; ++o) se += expf(lg[o] - mx);
        float lse = logf(se);
        float* op = OUT + (size_t)(row0 + t) * 10;
        #pragma unroll
        for (int o = 0; o < 10; ++o) op[o] = lg[o] - mx - lse;
    }
}

// ---------------------------------------------------------------------------
extern "C" void kernel_launch(void* const* d_in, const int* in_sizes, int n_in,
                              void* d_out, int out_size, void* d_ws, size_t ws_size,
                              hipStream_t stream)
{
    const float* X   = (const float*)d_in[0];
    const float* MRE = (const float*)d_in[1];
    const float* MIM = (const float*)d_in[2];
    const float* W1  = (const float*)d_in[3];
    const float* B1  = (const float*)d_in[4];
    const float* W4  = (const float*)d_in[5];
    const float* B4  = (const float*)d_in[6];
    float* OUT = (float*)d_out;

    float* kre  = (float*)d_ws;                          // 784 f32
    float* flag = kre + 784;                             // 1 f32
    u16*   w1p  = (u16*)((char*)d_ws + 4096);            // 1.28 MB
    u16*   w4p2 = (u16*)((char*)d_ws + 4096 + 1310720);  // 30720 B

    k_kre<<<1, 832, 0, stream>>>(MRE, MIM, kre, flag);
    k_w1pack<<<800, 128, 0, stream>>>(W1, kre, flag, w1p);
    k_w4pack2<<<8, 256, 0, stream>>>(W4, w4p2);
    k_main<<<512, 640, 0, stream>>>(X, w1p, w4p2, B1, B4, OUT);
}